// Round 15
// baseline (90.149 us; speedup 1.0000x reference)
//
#include <hip/hip_runtime.h>
#include <hip/hip_bf16.h>

#define B_ROWS 4096
#define D_DIM  256
#define TWO_B  8192
// reps row stride in bytes = 256 * 2 = 512

typedef float f32x4  __attribute__((ext_vector_type(4)));
typedef short bf16x8 __attribute__((ext_vector_type(8)));

#define CCHUNK  256
#define GY      (TWO_B / CCHUNK)    // 32 column chunks
#define MT      4                   // M-tiles (16 rows each) per wave = 64 rows
#define NT      (CCHUNK / 16)       // 16 col-tiles per WG

#define SC2 1442.6951f   // 1000 * log2(e)
#define M0  1442.6951f   // anchor: logit2 of sim == 1 (the diagonal)

// ---------------- kernel 1: normalize rows, compute positives, emit bf16 reps
__global__ __launch_bounds__(256) void k_prep(const float* __restrict__ p1,
                                              const float* __restrict__ p2,
                                              __hip_bfloat16* __restrict__ reps,
                                              float* __restrict__ pos) {
    const int r = blockIdx.x;
    const int t = threadIdx.x;
    float e1 = p1[r * D_DIM + t];
    float e2 = p2[r * D_DIM + t];
    float s11 = e1 * e1, s22 = e2 * e2, s12 = e1 * e2;
    #pragma unroll
    for (int m = 1; m < 64; m <<= 1) {
        s11 += __shfl_xor(s11, m);
        s22 += __shfl_xor(s22, m);
        s12 += __shfl_xor(s12, m);
    }
    __shared__ float red[3][4];
    const int w = t >> 6, l = t & 63;
    if (l == 0) { red[0][w] = s11; red[1][w] = s22; red[2][w] = s12; }
    __syncthreads();
    s11 = red[0][0] + red[0][1] + red[0][2] + red[0][3];
    s22 = red[1][0] + red[1][1] + red[1][2] + red[1][3];
    s12 = red[2][0] + red[2][1] + red[2][2] + red[2][3];
    const float n1 = fmaxf(sqrtf(s11), 1e-12f);
    const float n2 = fmaxf(sqrtf(s22), 1e-12f);
    reps[r * D_DIM + t]            = __float2bfloat16(e1 / n1);
    reps[(B_ROWS + r) * D_DIM + t] = __float2bfloat16(e2 / n2);
    if (t == 0) pos[r] = s12 / (n1 * n2);
}

// ---------------- kernel 2: fused reps·repsT -> row-wise sum of 2^(1443*sim - M0)
// NO LDS, NO barriers: reps is L2-resident (FETCH showed 16 MB total), so B-fragments
// load straight from L2 into registers, 2-deep pipelined (bfA/bfB, static names).
// WG: 4 waves x 64 rows = 256 rows; cols: CCHUNK per WG. Grid 32x32. Plain stores.
__global__ __launch_bounds__(256, 2) void k_simlse(const __hip_bfloat16* __restrict__ reps,
                                                   float* __restrict__ s_part) {
    const int t   = threadIdx.x;
    const int w   = t >> 6;
    const int l   = t & 63;
    const int c16 = l & 15;
    const int g   = l >> 4;     // 0..3

    const int row_base = blockIdx.x * 256 + w * 64;
    const int gy       = blockIdx.y;
    const int col_base = gy * CCHUNK;
    const char* repsB = (const char*)reps;

    // A fragments: 4 M-tiles x 8 k-steps, 16B per lane (AGPR/VGPR unified file)
    bf16x8 afrag[MT][8];
    #pragma unroll
    for (int mt = 0; mt < MT; ++mt) {
        const int arow = row_base + mt * 16 + c16;
        #pragma unroll
        for (int kk = 0; kk < 8; ++kk)
            afrag[mt][kk] = *(const bf16x8*)(repsB + (size_t)arow * 512 + kk * 64 + g * 16);
    }

    float s[4 * MT];
    #pragma unroll
    for (int i = 0; i < 4 * MT; ++i) s[i] = 0.f;

    // load one 16-col B tile (K=256) for this lane: col = ct + c16, bytes kk*64+g*16
    auto loadB = [&](bf16x8 (&bf)[8], int ct) {
        const char* base = repsB + (size_t)(ct + c16) * 512 + g * 16;
        #pragma unroll
        for (int kk = 0; kk < 8; ++kk)
            bf[kk] = *(const bf16x8*)(base + kk * 64);
    };

    auto computeT = [&](const bf16x8 (&bf)[8]) {
        f32x4 acc[MT];
        #pragma unroll
        for (int mt = 0; mt < MT; ++mt) acc[mt] = f32x4{0.f, 0.f, 0.f, 0.f};
        #pragma unroll
        for (int kk = 0; kk < 8; ++kk)
            #pragma unroll
            for (int mt = 0; mt < MT; ++mt)
                acc[mt] = __builtin_amdgcn_mfma_f32_16x16x32_bf16(afrag[mt][kk], bf[kk], acc[mt], 0, 0, 0);
        // D layout: row = g*4 + reg (within M-tile), col = c16
        float tmax = acc[0][0];
        #pragma unroll
        for (int mt = 0; mt < MT; ++mt)
            #pragma unroll
            for (int r = 0; r < 4; ++r) tmax = fmaxf(tmax, acc[mt][r]);
        // only tiles containing a diagonal element matter; dropped terms < 2^-144
        if (__any(tmax > 0.90f)) {
            #pragma unroll
            for (int mt = 0; mt < MT; ++mt)
                #pragma unroll
                for (int r = 0; r < 4; ++r)
                    s[mt * 4 + r] += exp2f(acc[mt][r] * SC2 - M0);
        }
    };

    bf16x8 bfA[8], bfB[8];
    loadB(bfA, col_base);
    #pragma unroll
    for (int tp = 0; tp < NT / 2; ++tp) {
        loadB(bfB, col_base + (tp * 2 + 1) * 16);     // prefetch odd tile
        computeT(bfA);                                // compute even tile
        if (tp * 2 + 2 < NT)
            loadB(bfA, col_base + (tp * 2 + 2) * 16); // prefetch next even
        computeT(bfB);                                // compute odd tile
    }

    // reduce s over the 16 lanes (cols) of each lane-group, then one plain store per row
    #pragma unroll
    for (int i = 0; i < 4 * MT; ++i) {
        #pragma unroll
        for (int m = 1; m < 16; m <<= 1) s[i] += __shfl_xor(s[i], m);
    }
    if (c16 == 0) {
        #pragma unroll
        for (int mt = 0; mt < MT; ++mt)
            #pragma unroll
            for (int r = 0; r < 4; ++r)
                s_part[(size_t)(row_base + mt * 16 + g * 4 + r) * GY + gy] = s[mt * 4 + r];
    }
}

// ---------------- kernel 3a: per-row reduce + per-WG loss partials. 32 WGs x 256.
__global__ __launch_bounds__(256) void k_red(const float* __restrict__ s_part,
                                             const float* __restrict__ pos,
                                             float* __restrict__ red_buf) {
    const float LN2 = 0.69314718f;
    const int wg = blockIdx.x;
    const int t  = threadIdx.x;
    const int r  = wg * 256 + t;
    const f32x4* p4 = (const f32x4*)(s_part + (size_t)r * GY);
    float srow = 0.f;
    #pragma unroll
    for (int i = 0; i < GY / 4; ++i) {
        const f32x4 a = p4[i];
        srow += (a[0] + a[1]) + (a[2] + a[3]);
    }
    float lsum = LN2 * (M0 + log2f(srow)) - 1000.0f * pos[r & (B_ROWS - 1)];
    float psum = (t < 128) ? pos[wg * 128 + t] : 0.f;
    #pragma unroll
    for (int m = 1; m < 64; m <<= 1) {
        lsum += __shfl_xor(lsum, m);
        psum += __shfl_xor(psum, m);
    }
    __shared__ float red[2][4];
    const int w = t >> 6, l = t & 63;
    if (l == 0) { red[0][w] = lsum; red[1][w] = psum; }
    __syncthreads();
    if (t == 0) {
        red_buf[wg]      = red[0][0] + red[0][1] + red[0][2] + red[0][3];
        red_buf[32 + wg] = red[1][0] + red[1][1] + red[1][2] + red[1][3];
    }
}

// ---------------- kernel 3b: final combine. 1 wave.
__global__ __launch_bounds__(64) void k_final2(const float* __restrict__ red_buf,
                                               float* __restrict__ out) {
    const int t = threadIdx.x;
    float v = (t < 32) ? red_buf[t] : red_buf[32 + (t - 32)];
    #pragma unroll
    for (int m = 1; m < 32; m <<= 1) v += __shfl_xor(v, m);
    if (t == 0)  out[0] = v / (float)TWO_B;   // lane 0 holds lsum total
    if (t == 32) out[1] = 2.0f * v;           // lane 32 holds psum total
}

extern "C" void kernel_launch(void* const* d_in, const int* in_sizes, int n_in,
                              void* d_out, int out_size, void* d_ws, size_t ws_size,
                              hipStream_t stream) {
    const float* p1 = (const float*)d_in[0];
    const float* p2 = (const float*)d_in[1];
    float* out = (float*)d_out;
    char* ws = (char*)d_ws;

    __hip_bfloat16* reps = (__hip_bfloat16*)ws;                               // 4 MiB
    float* pos     = (float*)(ws + (size_t)TWO_B * D_DIM * 2);                // 16 KiB
    float* s_part  = (float*)(ws + (size_t)TWO_B * D_DIM * 2 + B_ROWS * 4);   // 8192*32 fp32 = 1 MiB
    float* red_buf = s_part + (size_t)TWO_B * GY;                             // 64 floats

    k_prep<<<B_ROWS, 256, 0, stream>>>(p1, p2, reps, pos);
    dim3 g2(TWO_B / 256, GY);
    k_simlse<<<g2, 256, 0, stream>>>(reps, s_part);
    k_red<<<32, 256, 0, stream>>>(s_part, pos, red_buf);
    k_final2<<<1, 64, 0, stream>>>(red_buf, out);
}

// Round 46
// 53.470 us; speedup vs baseline: 1.6860x; 1.6860x over previous
//
#include <hip/hip_runtime.h>
#include <hip/hip_bf16.h>

#define B_ROWS 4096
#define D_DIM  256
#define TWO_B  8192
// reps row stride in bytes = 256 * 2 = 512

typedef float f32x4  __attribute__((ext_vector_type(4)));
typedef short bf16x8 __attribute__((ext_vector_type(8)));

#define CCHUNK      512
#define TPS         2               // 16-col tiles per LDS stage
#define STAGE_BYTES (TPS * 8192)    // 16 KiB per buffer, 3 buffers = 48 KiB
#define NSTAGES     (CCHUNK / (TPS * 16))   // 16
#define MT          4               // M-tiles (16 rows each) per wave = 64 rows
#define GY          (TWO_B / CCHUNK)  // 16 column chunks

#define SC2 1442.6951f   // 1000 * log2(e)
#define M0  1442.6951f   // anchor: logit2 of sim == 1 (the diagonal)

#define WAITVM(N) do { asm volatile("s_waitcnt vmcnt(" #N ")" ::: "memory"); \
                       __builtin_amdgcn_sched_barrier(0); } while (0)

__device__ __forceinline__ void async_copy16(void* lds_dst, const void* gsrc) {
    __builtin_amdgcn_global_load_lds(
        (__attribute__((address_space(1))) void*)(gsrc),
        (__attribute__((address_space(3))) void*)(lds_dst), 16, 0, 0);
}

// ---------------- kernel 1: normalize rows, compute positives, emit bf16 reps
__global__ __launch_bounds__(256) void k_prep(const float* __restrict__ p1,
                                              const float* __restrict__ p2,
                                              __hip_bfloat16* __restrict__ reps,
                                              float* __restrict__ pos) {
    const int r = blockIdx.x;
    const int t = threadIdx.x;
    float e1 = p1[r * D_DIM + t];
    float e2 = p2[r * D_DIM + t];
    float s11 = e1 * e1, s22 = e2 * e2, s12 = e1 * e2;
    #pragma unroll
    for (int m = 1; m < 64; m <<= 1) {
        s11 += __shfl_xor(s11, m);
        s22 += __shfl_xor(s22, m);
        s12 += __shfl_xor(s12, m);
    }
    __shared__ float red[3][4];
    const int w = t >> 6, l = t & 63;
    if (l == 0) { red[0][w] = s11; red[1][w] = s22; red[2][w] = s12; }
    __syncthreads();
    s11 = red[0][0] + red[0][1] + red[0][2] + red[0][3];
    s22 = red[1][0] + red[1][1] + red[1][2] + red[1][3];
    s12 = red[2][0] + red[2][1] + red[2][2] + red[2][3];
    const float n1 = fmaxf(sqrtf(s11), 1e-12f);
    const float n2 = fmaxf(sqrtf(s22), 1e-12f);
    reps[r * D_DIM + t]            = __float2bfloat16(e1 / n1);
    reps[(B_ROWS + r) * D_DIM + t] = __float2bfloat16(e2 / n2);
    if (t == 0) pos[r] = s12 / (n1 * n2);
}

// ---------------- kernel 2: fused reps·repsT -> row-wise sum of 2^(1443*sim - M0)
// WG: 4 waves x 64 rows (MT=4). 3-buffer LDS pipeline, ONE raw s_barrier and ONE
// counted s_waitcnt vmcnt(4) per stage (T4) — loads span 2 compute phases.
// Stage protocol per iter i: WAIT(4)[stage i landed] -> s_barrier[all waves landed +
// all done reading buf (i+2)%3 from iter i-1] -> issue stage i+2 -> compute stage i.
__global__ __launch_bounds__(256, 2) void k_simlse(const __hip_bfloat16* __restrict__ reps,
                                                   float* __restrict__ s_part) {
    __shared__ char lds[3][STAGE_BYTES];
    const int t   = threadIdx.x;
    const int w   = t >> 6;
    const int l   = t & 63;
    const int c16 = l & 15;
    const int g   = l >> 4;     // 0..3

    const int row_base = blockIdx.x * 256 + w * 64;
    const int gy       = blockIdx.y;
    const int col_base = gy * CCHUNK;
    const char* repsB = (const char*)reps;

    // A fragments: 4 M-tiles x 8 k-steps, 16B per lane
    bf16x8 afrag[MT][8];
    #pragma unroll
    for (int mt = 0; mt < MT; ++mt) {
        const int arow = row_base + mt * 16 + c16;
        #pragma unroll
        for (int kk = 0; kk < 8; ++kk)
            afrag[mt][kk] = *(const bf16x8*)(repsB + (size_t)arow * 512 + kk * 64 + g * 16);
    }

    float s[4 * MT];
    #pragma unroll
    for (int i = 0; i < 4 * MT; ++i) s[i] = 0.f;

    // stage TPS*16 cols x 256 k (bf16) into a buffer in fragment order.
    // 4 global_load_lds per thread => vmcnt +4 per stage.
    auto stage = [&](char* buf, int cstage) {
        #pragma unroll
        for (int i = 0; i < STAGE_BYTES / 4096; ++i) {
            const int a  = i * 4096 + w * 1024 + l * 16;
            const int tt = a >> 13;
            const int rr = a & 8191;
            const int kk = rr >> 10;
            const int gg = (rr >> 8) & 3;
            const int cc = (rr >> 4) & 15;
            const int col = cstage + tt * 16 + cc;
            async_copy16(buf + i * 4096 + w * 1024,            // wave-uniform base; HW adds lane*16
                         repsB + (size_t)col * 512 + kk * 64 + gg * 16);
        }
    };

    auto compute = [&](const char* buf) {
        #pragma unroll
        for (int tt = 0; tt < TPS; ++tt) {
            f32x4 acc[MT];
            #pragma unroll
            for (int mt = 0; mt < MT; ++mt) acc[mt] = f32x4{0.f, 0.f, 0.f, 0.f};
            #pragma unroll
            for (int kk = 0; kk < 8; ++kk) {
                const bf16x8 b = *(const bf16x8*)(buf + tt * 8192 + kk * 1024 + l * 16);
                #pragma unroll
                for (int mt = 0; mt < MT; ++mt)
                    acc[mt] = __builtin_amdgcn_mfma_f32_16x16x32_bf16(afrag[mt][kk], b, acc[mt], 0, 0, 0);
            }
            // D layout: row = g*4 + reg (within M-tile), col = c16
            float tmax = acc[0][0];
            #pragma unroll
            for (int mt = 0; mt < MT; ++mt)
                #pragma unroll
                for (int r = 0; r < 4; ++r) tmax = fmaxf(tmax, acc[mt][r]);
            // only tiles containing a diagonal element matter; dropped terms < 2^-144
            if (__any(tmax > 0.90f)) {
                #pragma unroll
                for (int mt = 0; mt < MT; ++mt)
                    #pragma unroll
                    for (int r = 0; r < 4; ++r)
                        s[mt * 4 + r] += exp2f(acc[mt][r] * SC2 - M0);
            }
        }
    };

    // prologue: fill buffers 0 and 1 (8 loads outstanding)
    stage(lds[0], col_base);
    stage(lds[1], col_base + TPS * 16);

    char* bA = lds[0];  // compute target (stage i)
    char* bB = lds[1];  // in flight (stage i+1)
    char* bC = lds[2];  // free -> stage i+2
    for (int st = 0; st < NSTAGES; ++st) {
        if (st + 2 < NSTAGES) {
            WAITVM(4);                         // stage st landed; st+1 still in flight
            __builtin_amdgcn_s_barrier();      // all waves landed + bC free of readers
            stage(bC, col_base + (st + 2) * (TPS * 16));
        } else if (st + 2 == NSTAGES) {
            WAITVM(4);
            __builtin_amdgcn_s_barrier();
        } else {                               // last stage: only its own loads remain
            WAITVM(0);
            __builtin_amdgcn_s_barrier();
        }
        compute(bA);
        char* tmp = bA; bA = bB; bB = bC; bC = tmp;
    }

    // reduce s over the 16 lanes (cols) of each lane-group, then one plain store per row
    #pragma unroll
    for (int i = 0; i < 4 * MT; ++i) {
        #pragma unroll
        for (int m = 1; m < 16; m <<= 1) s[i] += __shfl_xor(s[i], m);
    }
    if (c16 == 0) {
        #pragma unroll
        for (int mt = 0; mt < MT; ++mt)
            #pragma unroll
            for (int r = 0; r < 4; ++r)
                s_part[(size_t)(row_base + mt * 16 + g * 4 + r) * GY + gy] = s[mt * 4 + r];
    }
}

// ---------------- kernel 3a: per-row reduce + per-WG loss partials. 32 WGs x 256.
__global__ __launch_bounds__(256) void k_red(const float* __restrict__ s_part,
                                             const float* __restrict__ pos,
                                             float* __restrict__ red_buf) {
    const float LN2 = 0.69314718f;
    const int wg = blockIdx.x;
    const int t  = threadIdx.x;
    const int r  = wg * 256 + t;
    const f32x4* p4 = (const f32x4*)(s_part + (size_t)r * GY);
    float srow = 0.f;
    #pragma unroll
    for (int i = 0; i < GY / 4; ++i) {
        const f32x4 a = p4[i];
        srow += (a[0] + a[1]) + (a[2] + a[3]);
    }
    float lsum = LN2 * (M0 + log2f(srow)) - 1000.0f * pos[r & (B_ROWS - 1)];
    float psum = (t < 128) ? pos[wg * 128 + t] : 0.f;
    #pragma unroll
    for (int m = 1; m < 64; m <<= 1) {
        lsum += __shfl_xor(lsum, m);
        psum += __shfl_xor(psum, m);
    }
    __shared__ float red[2][4];
    const int w = t >> 6, l = t & 63;
    if (l == 0) { red[0][w] = lsum; red[1][w] = psum; }
    __syncthreads();
    if (t == 0) {
        red_buf[wg]      = red[0][0] + red[0][1] + red[0][2] + red[0][3];
        red_buf[32 + wg] = red[1][0] + red[1][1] + red[1][2] + red[1][3];
    }
}

// ---------------- kernel 3b: final combine. 1 wave.
__global__ __launch_bounds__(64) void k_final2(const float* __restrict__ red_buf,
                                               float* __restrict__ out) {
    const int t = threadIdx.x;
    float v = (t < 32) ? red_buf[t] : red_buf[32 + (t - 32)];
    #pragma unroll
    for (int m = 1; m < 32; m <<= 1) v += __shfl_xor(v, m);
    if (t == 0)  out[0] = v / (float)TWO_B;   // lane 0 holds lsum total
    if (t == 32) out[1] = 2.0f * v;           // lane 32 holds psum total
}

extern "C" void kernel_launch(void* const* d_in, const int* in_sizes, int n_in,
                              void* d_out, int out_size, void* d_ws, size_t ws_size,
                              hipStream_t stream) {
    const float* p1 = (const float*)d_in[0];
    const float* p2 = (const float*)d_in[1];
    float* out = (float*)d_out;
    char* ws = (char*)d_ws;

    __hip_bfloat16* reps = (__hip_bfloat16*)ws;                               // 4 MiB
    float* pos     = (float*)(ws + (size_t)TWO_B * D_DIM * 2);                // 16 KiB
    float* s_part  = (float*)(ws + (size_t)TWO_B * D_DIM * 2 + B_ROWS * 4);   // 8192*16 fp32 = 512 KiB
    float* red_buf = s_part + (size_t)TWO_B * GY;                             // 64 floats

    k_prep<<<B_ROWS, 256, 0, stream>>>(p1, p2, reps, pos);
    dim3 g2(TWO_B / 256, GY);
    k_simlse<<<g2, 256, 0, stream>>>(reps, s_part);
    k_red<<<32, 256, 0, stream>>>(s_part, pos, red_buf);
    k_final2<<<1, 64, 0, stream>>>(red_buf, out);
}